// Round 24
// baseline (213.876 us; speedup 1.0000x reference)
//
#include <hip/hip_runtime.h>

#define D   64
#define H   8
#define DH  8
#define ED  16
#define QK_SCALE 0.35355339059327373f   // 1/sqrt(8)

typedef unsigned int uint_t;
typedef __attribute__((ext_vector_type(8))) short bf16x8;   // 8 bf16 (4 VGPRs)
typedef __attribute__((ext_vector_type(4))) float f32x4;

__device__ __forceinline__ uint_t f2bf(float f) {           // RNE f32->bf16
    uint_t u = __float_as_uint(f);
    return (u + 0x7FFFu + ((u >> 16) & 1u)) >> 16;
}
__device__ __forceinline__ float bf_lo(uint_t u) { return __uint_as_float(u << 16); }
__device__ __forceinline__ float bf_hi(uint_t u) { return __uint_as_float(u & 0xFFFF0000u); }

// keep-half transpose reduce: lane (e,h) ends with sum over e' of acc_e'[e]
__device__ __forceinline__ float khreduce8(const float* acc, int e) {
    int b0 = e & 1, b1 = (e >> 1) & 1, b2 = (e >> 2) & 1;
    float t0[4];
    #pragma unroll
    for (int j = 0; j < 4; ++j) {
        float k = b0 ? acc[2*j+1] : acc[2*j];
        float s = b0 ? acc[2*j]   : acc[2*j+1];
        t0[j] = k + __shfl_xor(s, 8);
    }
    float t1[2];
    #pragma unroll
    for (int j = 0; j < 2; ++j) {
        float k = b1 ? t0[2*j+1] : t0[2*j];
        float s = b1 ? t0[2*j]   : t0[2*j+1];
        t1[j] = k + __shfl_xor(s, 16);
    }
    float k = b2 ? t1[1] : t1[0];
    float s = b2 ? t1[0] : t1[1];
    return k + __shfl_xor(s, 32);
}

// ---------------------------------------------------------------------------
// K1 fused: [csr_hist | proj_qs MFMA]
//   q/xr GEMMs on matrix cores (clone of validated kv MFMA structure).
//   qxr packed: lo = q*QK_SCALE (bf16), hi = xr (bf16).
// ---------------------------------------------------------------------------
__global__ __launch_bounds__(256) void proj_qs_hist(
    const float* __restrict__ x,
    const float* __restrict__ Wq, const float* __restrict__ bq,
    const float* __restrict__ Ws, const float* __restrict__ bs,
    uint_t* __restrict__ qxr, int N,
    const int* __restrict__ ei, int* __restrict__ cnt, int E, int histB,
    int qsBlocks)
{
    if (blockIdx.x < histB) {
        int gid = blockIdx.x * 256 + threadIdx.x;
        if (gid < E) atomicAdd(&cnt[ei[E + gid]], 1);
        return;
    }
    int pb   = blockIdx.x - histB;
    int lane = threadIdx.x & 63;
    int wv   = threadIdx.x >> 6;
    int l = lane & 15, g = lane >> 4;

    bf16x8 Bf[2][4][2];
    #pragma unroll
    for (int ct = 0; ct < 4; ++ct)
        #pragma unroll
        for (int kh = 0; kh < 2; ++kh)
            #pragma unroll
            for (int j = 0; j < 8; ++j) {
                int k = kh * 32 + g * 8 + j;
                int c = ct * 16 + l;
                Bf[0][ct][kh][j] = (short)f2bf(Wq[k * 64 + c]);
                Bf[1][ct][kh][j] = (short)f2bf(Ws[k * 64 + c]);
            }
    float bqc[4], bsc[4];
    #pragma unroll
    for (int ct = 0; ct < 4; ++ct) {
        bqc[ct] = bq[ct * 16 + l];
        bsc[ct] = bs[ct * 16 + l];
    }

    int nt   = (N + 15) >> 4;
    int wtot = qsBlocks * 4;
    for (int t = pb * 4 + wv; t < nt; t += wtot) {
        int n0 = t * 16;
        bf16x8 Af[2];
        const float* xr = x + (size_t)(n0 + l) * 64 + g * 8;
        #pragma unroll
        for (int kh = 0; kh < 2; ++kh) {
            float4 p0 = *(const float4*)(xr + kh * 32);
            float4 p1 = *(const float4*)(xr + kh * 32 + 4);
            Af[kh][0] = (short)f2bf(p0.x); Af[kh][1] = (short)f2bf(p0.y);
            Af[kh][2] = (short)f2bf(p0.z); Af[kh][3] = (short)f2bf(p0.w);
            Af[kh][4] = (short)f2bf(p1.x); Af[kh][5] = (short)f2bf(p1.y);
            Af[kh][6] = (short)f2bf(p1.z); Af[kh][7] = (short)f2bf(p1.w);
        }
        #pragma unroll
        for (int ct = 0; ct < 4; ++ct) {
            f32x4 cq = {0.f, 0.f, 0.f, 0.f};
            f32x4 cx = {0.f, 0.f, 0.f, 0.f};
            cq = __builtin_amdgcn_mfma_f32_16x16x32_bf16(Af[0], Bf[0][ct][0], cq, 0, 0, 0);
            cq = __builtin_amdgcn_mfma_f32_16x16x32_bf16(Af[1], Bf[0][ct][1], cq, 0, 0, 0);
            cx = __builtin_amdgcn_mfma_f32_16x16x32_bf16(Af[0], Bf[1][ct][0], cx, 0, 0, 0);
            cx = __builtin_amdgcn_mfma_f32_16x16x32_bf16(Af[1], Bf[1][ct][1], cx, 0, 0, 0);
            #pragma unroll
            for (int r = 0; r < 4; ++r) {
                int node = n0 + g * 4 + r;
                uint_t pk = f2bf((cq[r] + bqc[ct]) * QK_SCALE)
                          | (f2bf(cx[r] + bsc[ct]) << 16);
                qxr[(size_t)node * 64 + ct * 16 + l] = pk;
            }
        }
    }
}

// ---------------------------------------------------------------------------
// K2 fused: [proj_kv MFMA | scan_a | aproj]
//   aproj: wave per node (R5-proven), A[h,i]=sum_dh q[8h+dh]*We[i,8h+dh]
//   reading q from qxr lo halves; writes Ap packed + qbe.
// ---------------------------------------------------------------------------
__global__ __launch_bounds__(256) void proj_kv_scana(
    const float* __restrict__ x,
    const float* __restrict__ Wk, const float* __restrict__ bk,
    const float* __restrict__ Wv, const float* __restrict__ bv,
    const float* __restrict__ We, const float* __restrict__ be,
    const uint_t* __restrict__ qxr,
    uint_t* __restrict__ kvp, uint_t* __restrict__ Ap,
    float* __restrict__ qbe, int N, int kvBlocks, int scanBlocks,
    const int* __restrict__ cnt, int* __restrict__ bsum)
{
    __shared__ int   red[256];
    __shared__ float sWe[ED * D];   // 4 KB
    __shared__ float sbe[D];
    if (blockIdx.x >= kvBlocks && blockIdx.x < kvBlocks + scanBlocks) {
        int t = threadIdx.x;
        int i = (blockIdx.x - kvBlocks) * 256 + t;
        red[t] = (i < N) ? cnt[i] : 0;
        __syncthreads();
        for (int s = 128; s > 0; s >>= 1) {
            if (t < s) red[t] += red[t + s];
            __syncthreads();
        }
        if (t == 0) bsum[blockIdx.x - kvBlocks] = red[0];
        return;
    }
    if (blockIdx.x >= kvBlocks + scanBlocks) {
        // ---- aproj segment: 4 nodes/block, wave per node ----
        for (int t = threadIdx.x; t < ED * D; t += 256) sWe[t] = We[t];
        if (threadIdx.x < D) sbe[threadIdx.x] = be[threadIdx.x];
        __syncthreads();

        int lane = threadIdx.x & 63;
        int nid  = (blockIdx.x - kvBlocks - scanBlocks) * 4 + (threadIdx.x >> 6);
        if (nid >= N) return;

        int h = lane >> 3, t = lane & 7;
        float qv = bf_lo(qxr[(size_t)nid * 64 + lane]);   // q (pre-scaled)
        float a0 = 0.f, a1 = 0.f, qb = 0.f;
        #pragma unroll
        for (int dh = 0; dh < 8; ++dh) {
            float qd = __shfl(qv, (lane & 56) + dh);
            a0 += qd * sWe[(2 * t)     * D + h * 8 + dh];
            a1 += qd * sWe[(2 * t + 1) * D + h * 8 + dh];
            qb += qd * sbe[h * 8 + dh];
        }
        Ap[(size_t)nid * 64 + lane] = f2bf(a0) | (f2bf(a1) << 16);
        if (t == 0) qbe[(size_t)nid * 8 + h] = qb;
        return;
    }

    // ---- kv MFMA segment ----
    int lane = threadIdx.x & 63;
    int wv   = threadIdx.x >> 6;
    int l = lane & 15, g = lane >> 4;

    bf16x8 Bf[2][4][2];
    #pragma unroll
    for (int ct = 0; ct < 4; ++ct)
        #pragma unroll
        for (int kh = 0; kh < 2; ++kh)
            #pragma unroll
            for (int j = 0; j < 8; ++j) {
                int k = kh * 32 + g * 8 + j;
                int c = ct * 16 + l;
                Bf[0][ct][kh][j] = (short)f2bf(Wk[k * 64 + c]);
                Bf[1][ct][kh][j] = (short)f2bf(Wv[k * 64 + c]);
            }
    float bkc[4], bvc[4];
    #pragma unroll
    for (int ct = 0; ct < 4; ++ct) {
        bkc[ct] = bk[ct * 16 + l];
        bvc[ct] = bv[ct * 16 + l];
    }

    int nt   = (N + 15) >> 4;
    int wtot = kvBlocks * 4;
    for (int t = blockIdx.x * 4 + wv; t < nt; t += wtot) {
        int n0 = t * 16;
        bf16x8 Af[2];
        const float* xr = x + (size_t)(n0 + l) * 64 + g * 8;
        #pragma unroll
        for (int kh = 0; kh < 2; ++kh) {
            float4 p0 = *(const float4*)(xr + kh * 32);
            float4 p1 = *(const float4*)(xr + kh * 32 + 4);
            Af[kh][0] = (short)f2bf(p0.x); Af[kh][1] = (short)f2bf(p0.y);
            Af[kh][2] = (short)f2bf(p0.z); Af[kh][3] = (short)f2bf(p0.w);
            Af[kh][4] = (short)f2bf(p1.x); Af[kh][5] = (short)f2bf(p1.y);
            Af[kh][6] = (short)f2bf(p1.z); Af[kh][7] = (short)f2bf(p1.w);
        }
        #pragma unroll
        for (int ct = 0; ct < 4; ++ct) {
            f32x4 ck = {0.f, 0.f, 0.f, 0.f};
            f32x4 cv = {0.f, 0.f, 0.f, 0.f};
            ck = __builtin_amdgcn_mfma_f32_16x16x32_bf16(Af[0], Bf[0][ct][0], ck, 0, 0, 0);
            ck = __builtin_amdgcn_mfma_f32_16x16x32_bf16(Af[1], Bf[0][ct][1], ck, 0, 0, 0);
            cv = __builtin_amdgcn_mfma_f32_16x16x32_bf16(Af[0], Bf[1][ct][0], cv, 0, 0, 0);
            cv = __builtin_amdgcn_mfma_f32_16x16x32_bf16(Af[1], Bf[1][ct][1], cv, 0, 0, 0);
            #pragma unroll
            for (int r = 0; r < 4; ++r) {
                int node = n0 + g * 4 + r;
                uint_t pk = f2bf(ck[r] + bkc[ct]) | (f2bf(cv[r] + bvc[ct]) << 16);
                kvp[(size_t)node * 64 + ct * 16 + l] = pk;
            }
        }
    }
}

// ---------------------------------------------------------------------------
// scan_c (merged with scan_b): every block redundantly scans the block sums.
// ---------------------------------------------------------------------------
__global__ __launch_bounds__(256) void scan_c(
    const int* __restrict__ cnt, const int* __restrict__ bsum,
    int* __restrict__ row_start, int* __restrict__ cursor, int N, int E, int nb)
{
    __shared__ int sb[256];
    __shared__ int sh[256];
    int t = threadIdx.x;
    int bv = (t < nb) ? bsum[t] : 0;
    sb[t] = bv;
    __syncthreads();
    for (int s = 1; s < 256; s <<= 1) {
        int a = (t >= s) ? sb[t - s] : 0;
        __syncthreads();
        sb[t] += a;
        __syncthreads();
    }
    int boff = sb[blockIdx.x] - bsum[blockIdx.x];   // exclusive block offset

    int i = blockIdx.x * 256 + t;
    int v = (i < N) ? cnt[i] : 0;
    sh[t] = v;
    __syncthreads();
    for (int s = 1; s < 256; s <<= 1) {
        int a = (t >= s) ? sh[t - s] : 0;
        __syncthreads();
        sh[t] += a;
        __syncthreads();
    }
    int excl = sh[t] - v + boff;
    if (i < N) { row_start[i] = excl; cursor[i] = excl; }
    if (i == N - 1) row_start[N] = E;
}

// ---------------------------------------------------------------------------
// K5: payload scatter. srcs_s[pos] + ea_s[pos] (bf16 row) in CSR order.
// ---------------------------------------------------------------------------
__global__ __launch_bounds__(256) void csr_scatter(
    const int* __restrict__ ei, const float4* __restrict__ ea4,
    int* __restrict__ cursor, int* __restrict__ srcs_s,
    uint_t* __restrict__ ea_s, int E)
{
    int gid = blockIdx.x * 256 + threadIdx.x;
    if (gid >= E) return;
    int src = ei[gid];
    int dst = ei[E + gid];
    float4 r0 = ea4[(size_t)gid * 4 + 0];
    float4 r1 = ea4[(size_t)gid * 4 + 1];
    float4 r2 = ea4[(size_t)gid * 4 + 2];
    float4 r3 = ea4[(size_t)gid * 4 + 3];
    int pos = atomicAdd(&cursor[dst], 1);
    srcs_s[pos] = src;
    uint4 p0, p1;
    p0.x = f2bf(r0.x) | (f2bf(r0.y) << 16);
    p0.y = f2bf(r0.z) | (f2bf(r0.w) << 16);
    p0.z = f2bf(r1.x) | (f2bf(r1.y) << 16);
    p0.w = f2bf(r1.z) | (f2bf(r1.w) << 16);
    p1.x = f2bf(r2.x) | (f2bf(r2.y) << 16);
    p1.y = f2bf(r2.z) | (f2bf(r2.w) << 16);
    p1.z = f2bf(r3.x) | (f2bf(r3.y) << 16);
    p1.w = f2bf(r3.z) | (f2bf(r3.w) << 16);
    *(uint4*)(ea_s + (size_t)pos * 8)     = p0;
    *(uint4*)(ea_s + (size_t)pos * 8 + 4) = p1;
}

// ---------------------------------------------------------------------------
// K6: pull gather (R18/R20 best config, unchanged).
// ---------------------------------------------------------------------------
__global__ __launch_bounds__(256, 4) void node_gather(
    const int*   __restrict__ row_start, // [N+1]
    const int*   __restrict__ srcs_s,    // [E] CSR-ordered src
    const uint_t* __restrict__ ea_s,     // [E*8] CSR-ordered bf16x2
    const float* __restrict__ We, const float* __restrict__ be,
    const uint_t* __restrict__ qxr, const uint_t* __restrict__ kvp,
    const uint_t* __restrict__ Ap, const float* __restrict__ qbe,
    const float* __restrict__ Wbeta,
    float* __restrict__ out, float* __restrict__ S1p, float* __restrict__ S2p,
    int N)
{
    __shared__ float l1[4][D];
    __shared__ float l2[4][D];
    int lane = threadIdx.x & 63;
    int w    = threadIdx.x >> 6;
    int h    = lane & 7;
    int e    = lane >> 3;
    int cmix = h * 8 + e;

    float w0[8], w1[8];
    #pragma unroll
    for (int j = 0; j < 8; ++j) {
        w0[j] = We[(2 * e)     * D + h * 8 + j];
        w1[j] = We[(2 * e + 1) * D + h * 8 + j];
    }
    float bev = be[cmix];
    float wb0 = Wbeta[cmix], wb1 = Wbeta[D + cmix], wb2 = Wbeta[2 * D + cmix];

    float s1bn = 0.f, s2bn = 0.f;
    int stride = gridDim.x * 4;

    for (int nid = blockIdx.x * 4 + w; nid < N; nid += stride) {
        int rs  = row_start[nid];
        int deg = row_start[nid + 1] - rs;

        const uint4* qxp = (const uint4*)(qxr + (size_t)nid * D + h * 8);
        uint4 qx0 = qxp[0], qx1 = qxp[1];
        float q8[8];
        q8[0] = bf_lo(qx0.x); q8[1] = bf_lo(qx0.y);
        q8[2] = bf_lo(qx0.z); q8[3] = bf_lo(qx0.w);
        q8[4] = bf_lo(qx1.x); q8[5] = bf_lo(qx1.y);
        q8[6] = bf_lo(qx1.z); q8[7] = bf_lo(qx1.w);
        uint_t xru0 = (e & 2) ? ((e & 1) ? qx0.w : qx0.z)
                              : ((e & 1) ? qx0.y : qx0.x);
        uint_t xru1 = (e & 2) ? ((e & 1) ? qx1.w : qx1.z)
                              : ((e & 1) ? qx1.y : qx1.x);
        float xrv = bf_hi((e & 4) ? xru1 : xru0);

        const uint4* app = (const uint4*)(Ap + (size_t)nid * 64 + h * 8);
        uint4 au0 = app[0], au1 = app[1];
        float a16[ED];
        #pragma unroll
        for (int j = 0; j < 4; ++j) {
            a16[j * 2]         = bf_lo((&au0.x)[j]);
            a16[j * 2 + 1]     = bf_hi((&au0.x)[j]);
            a16[8 + j * 2]     = bf_lo((&au1.x)[j]);
            a16[8 + j * 2 + 1] = bf_hi((&au1.x)[j]);
        }
        float qbeh = qbe[(size_t)nid * 8 + h];

        float acc[8] = {0,0,0,0,0,0,0,0};
        float sv[ED] = {0,0,0,0,0,0,0,0,0,0,0,0,0,0,0,0};
        float den = 0.f;

        int src_next = (e < deg) ? srcs_s[rs + e] : 0;

        for (int j0 = 0; j0 < deg; j0 += 8) {
            int src = src_next;
            {
                int enx = j0 + 8 + e;
                src_next = (enx < deg) ? srcs_s[rs + enx] : 0;
            }
            int eidx = j0 + e;
            bool valid = eidx < deg;
            int ce = valid ? eidx : 0;

            const uint4* kp = (const uint4*)(kvp + (size_t)src * 64 + h * 8);
            uint4 k0 = kp[0], k1 = kp[1];
            const uint4* ep = (const uint4*)(ea_s + (size_t)(rs + ce) * 8);
            uint4 u0 = ep[0], u1 = ep[1];

            float ex[ED];
            #pragma unroll
            for (int j = 0; j < 4; ++j) {
                ex[j * 2]         = bf_lo((&u0.x)[j]);
                ex[j * 2 + 1]     = bf_hi((&u0.x)[j]);
                ex[8 + j * 2]     = bf_lo((&u1.x)[j]);
                ex[8 + j * 2 + 1] = bf_hi((&u1.x)[j]);
            }
            float c = qbeh;
            c += q8[0] * bf_lo(k0.x); c += q8[1] * bf_lo(k0.y);
            c += q8[2] * bf_lo(k0.z); c += q8[3] * bf_lo(k0.w);
            c += q8[4] * bf_lo(k1.x); c += q8[5] * bf_lo(k1.y);
            c += q8[6] * bf_lo(k1.z); c += q8[7] * bf_lo(k1.w);
            #pragma unroll
            for (int i = 0; i < ED; ++i) c += ex[i] * a16[i];

            float p = valid ? __expf(c) : 0.f;
            den += p;
            acc[0] += p * bf_hi(k0.x); acc[1] += p * bf_hi(k0.y);
            acc[2] += p * bf_hi(k0.z); acc[3] += p * bf_hi(k0.w);
            acc[4] += p * bf_hi(k1.x); acc[5] += p * bf_hi(k1.y);
            acc[6] += p * bf_hi(k1.z); acc[7] += p * bf_hi(k1.w);
            #pragma unroll
            for (int i = 0; i < ED; ++i) sv[i] += p * ex[i];
        }

        den += __shfl_xor(den, 8);
        den += __shfl_xor(den, 16);
        den += __shfl_xor(den, 32);

        float u[8];
        #pragma unroll
        for (int j = 0; j < 8; ++j) {
            int i0 = ((j & 6) << 1) | (j & 1);
            float k = (e & 1) ? sv[i0 | 2] : sv[i0];
            float s = (e & 1) ? sv[i0] : sv[i0 | 2];
            u[j] = k + __shfl_xor(s, 8);
        }
        float v2[4];
        #pragma unroll
        for (int j = 0; j < 4; ++j) {
            int j0 = ((j & 2) << 1) | (j & 1);
            float k = (e & 2) ? u[j0 | 2] : u[j0];
            float s = (e & 2) ? u[j0] : u[j0 | 2];
            v2[j] = k + __shfl_xor(s, 16);
        }
        float S0, S1;
        {
            float k0 = (e & 4) ? v2[2] : v2[0];
            float s0 = (e & 4) ? v2[0] : v2[2];
            S0 = k0 + __shfl_xor(s0, 32);
            float k1 = (e & 4) ? v2[3] : v2[1];
            float s1 = (e & 4) ? v2[1] : v2[3];
            S1 = k1 + __shfl_xor(s1, 32);
        }

        float cj[8];
        #pragma unroll
        for (int j = 0; j < 8; ++j) cj[j] = S0 * w0[j] + S1 * w1[j];
        float esum = khreduce8(cj, e);
        float vsum = khreduce8(acc, e);

        float o = (vsum + esum + bev * den) / (den + 1e-16f);

        float tb  = o * wb0 + xrv * wb1 + (o - xrv) * wb2;
        #pragma unroll
        for (int s = 1; s < 64; s <<= 1) tb += __shfl_xor(tb, s);
        float g  = 1.f / (1.f + __expf(-tb));
        float o2 = g * xrv + (1.f - g) * o;
        out[(size_t)nid * D + cmix] = o2;
        s1bn += o2; s2bn += o2 * o2;
    }

    l1[w][cmix] = s1bn; l2[w][cmix] = s2bn;
    __syncthreads();
    if (threadIdx.x < D) {
        float a = l1[0][threadIdx.x] + l1[1][threadIdx.x]
                + l1[2][threadIdx.x] + l1[3][threadIdx.x];
        float b = l2[0][threadIdx.x] + l2[1][threadIdx.x]
                + l2[2][threadIdx.x] + l2[3][threadIdx.x];
        unsafeAtomicAdd(&S1p[threadIdx.x * 64], a);
        unsafeAtomicAdd(&S2p[threadIdx.x * 64], b);
    }
}

// ---------------------------------------------------------------------------
// K7: batchnorm finalize + apply + LeakyReLU, float4 in place on d_out.
// ---------------------------------------------------------------------------
__global__ __launch_bounds__(256) void bn_apply(
    float4* __restrict__ out, const float* __restrict__ S1p,
    const float* __restrict__ S2p, const float* __restrict__ gamma,
    const float* __restrict__ beta, int total4, float invN)
{
    int gid = blockIdx.x * 256 + threadIdx.x;
    if (gid >= total4) return;
    int col = (gid & 15) * 4;
    float4 g4 = *(const float4*)(gamma + col);
    float4 b4 = *(const float4*)(beta + col);
    float4 y  = out[gid];
    #pragma unroll
    for (int j = 0; j < 4; ++j) {
        float mean = S1p[(col + j) * 64] * invN;
        float var  = S2p[(col + j) * 64] * invN - mean * mean;
        float sc   = (&g4.x)[j] * rsqrtf(var + 1e-5f);
        float sh   = (&b4.x)[j] - mean * sc;
        float tv   = (&y.x)[j] * sc + sh;
        (&y.x)[j]  = (tv >= 0.f) ? tv : 0.01f * tv;
    }
    out[gid] = y;
}

// ---------------------------------------------------------------------------
extern "C" void kernel_launch(void* const* d_in, const int* in_sizes, int n_in,
                              void* d_out, int out_size, void* d_ws, size_t ws_size,
                              hipStream_t stream)
{
    const float* x     = (const float*)d_in[0];
    const int*   ei    = (const int*)  d_in[1];
    const float* ea    = (const float*)d_in[2];
    const float* Wq    = (const float*)d_in[3];
    const float* bq    = (const float*)d_in[4];
    const float* Wk    = (const float*)d_in[5];
    const float* bk    = (const float*)d_in[6];
    const float* Wv    = (const float*)d_in[7];
    const float* bv    = (const float*)d_in[8];
    const float* We    = (const float*)d_in[9];
    const float* be    = (const float*)d_in[10];
    const float* Wskip = (const float*)d_in[11];
    const float* bskip = (const float*)d_in[12];
    const float* Wbeta = (const float*)d_in[13];
    const float* gamma = (const float*)d_in[14];
    const float* betab = (const float*)d_in[15];

    int N = in_sizes[0] / D;   // 50000
    int E = in_sizes[1] / 2;   // 800000

    // ws layout (uint units)
    int*    ws        = (int*)d_ws;
    int*    cnt       = ws;                         // 50000 (also scatter cursor)
    float*  S1p       = (float*)(ws + 50000);       // 4096 padded col sums
    float*  S2p       = (float*)(ws + 54096);       // 4096
    int*    row_start = ws + 58192;                 // 50004
    int*    bsum      = ws + 108240;                // 256 (16B aligned)
    int*    srcs_s    = ws + 108544;                // 800000
    uint_t* ea_s      = (uint_t*)(ws + 908544);     // 6400000
    uint_t* kvp       = (uint_t*)(ws + 7308544);    // 3200000
    uint_t* qxr       = (uint_t*)(ws + 10508544);   // 3200000 (packed q|xr)
    uint_t* Ap        = (uint_t*)(ws + 13708544);   // 3200000
    float*  qbe       = (float*)(ws + 16908544);    // 400000

    // zero cnt + S1p + S2p (contiguous)
    hipMemsetAsync(d_ws, 0, (size_t)58192 * sizeof(int), stream);

    int histB = (E + 255) / 256;    // 3125
    int qsB   = 196;                // MFMA waves: 784
    proj_qs_hist<<<histB + qsB, 256, 0, stream>>>(
        x, Wq, bq, Wskip, bskip, qxr, N, ei, cnt, E, histB, qsB);

    int scanB  = (N + 255) / 256;   // 196
    int kvB    = 196;
    int aprojB = (N + 3) / 4;       // 12500
    proj_kv_scana<<<kvB + scanB + aprojB, 256, 0, stream>>>(
        x, Wk, bk, Wv, bv, We, be, qxr,
        kvp, Ap, qbe, N, kvB, scanB, cnt, bsum);

    scan_c<<<scanB, 256, 0, stream>>>(cnt, bsum, row_start, cnt, N, E, scanB);

    csr_scatter<<<(E + 255) / 256, 256, 0, stream>>>(
        ei, (const float4*)ea, cnt, srcs_s, ea_s, E);

    node_gather<<<1024, 256, 0, stream>>>(
        row_start, srcs_s, ea_s, We, be, qxr, kvp, Ap, qbe, Wbeta,
        (float*)d_out, S1p, S2p, N);

    bn_apply<<<(N * 16 + 255) / 256, 256, 0, stream>>>(
        (float4*)d_out, S1p, S2p, gamma, betab, N * 16, 1.0f / (float)N);
}

// Round 25
// 187.528 us; speedup vs baseline: 1.1405x; 1.1405x over previous
//
#include <hip/hip_runtime.h>

#define D   64
#define H   8
#define DH  8
#define ED  16
#define QK_SCALE 0.35355339059327373f   // 1/sqrt(8)

typedef unsigned int uint_t;
typedef __attribute__((ext_vector_type(8))) short bf16x8;   // 8 bf16 (4 VGPRs)
typedef __attribute__((ext_vector_type(4))) float f32x4;

__device__ __forceinline__ void fma4(float4& a, float s, const float4& w) {
    a.x += s * w.x; a.y += s * w.y; a.z += s * w.z; a.w += s * w.w;
}
__device__ __forceinline__ uint_t f2bf(float f) {           // RNE f32->bf16
    uint_t u = __float_as_uint(f);
    return (u + 0x7FFFu + ((u >> 16) & 1u)) >> 16;
}
__device__ __forceinline__ float bf_lo(uint_t u) { return __uint_as_float(u << 16); }
__device__ __forceinline__ float bf_hi(uint_t u) { return __uint_as_float(u & 0xFFFF0000u); }

// keep-half transpose reduce: lane (e,h) ends with sum over e' of acc_e'[e]
__device__ __forceinline__ float khreduce8(const float* acc, int e) {
    int b0 = e & 1, b1 = (e >> 1) & 1, b2 = (e >> 2) & 1;
    float t0[4];
    #pragma unroll
    for (int j = 0; j < 4; ++j) {
        float k = b0 ? acc[2*j+1] : acc[2*j];
        float s = b0 ? acc[2*j]   : acc[2*j+1];
        t0[j] = k + __shfl_xor(s, 8);
    }
    float t1[2];
    #pragma unroll
    for (int j = 0; j < 2; ++j) {
        float k = b1 ? t0[2*j+1] : t0[2*j];
        float s = b1 ? t0[2*j]   : t0[2*j+1];
        t1[j] = k + __shfl_xor(s, 16);
    }
    float k = b2 ? t1[1] : t1[0];
    float s = b2 ? t1[0] : t1[1];
    return k + __shfl_xor(s, 32);
}

// ---------------------------------------------------------------------------
// K1 fused: [proj_qs blocks | csr_hist blocks]
// ---------------------------------------------------------------------------
__global__ __launch_bounds__(256) void proj_qs_hist(
    const float* __restrict__ x,
    const float* __restrict__ Wq, const float* __restrict__ bq,
    const float* __restrict__ Ws, const float* __restrict__ bs,
    const float* __restrict__ We, const float* __restrict__ be,
    uint_t* __restrict__ qxr,
    uint_t* __restrict__ Ap, float* __restrict__ qbe, int N,
    const int* __restrict__ ei, int* __restrict__ cnt, int E, int projBlocks)
{
    __shared__ float sW[2][D * D];          // 32 KB
    __shared__ float sWe[ED * D];           // 4 KB
    __shared__ float sbe[D];
    if (blockIdx.x >= projBlocks) {
        int gid = (blockIdx.x - projBlocks) * 256 + threadIdx.x;
        if (gid < E) atomicAdd(&cnt[ei[E + gid]], 1);
        return;
    }
    {
        for (int t = threadIdx.x; t < D * D; t += 256) {
            sW[0][t] = Wq[t];
            sW[1][t] = Ws[t];
        }
        for (int t = threadIdx.x; t < ED * D; t += 256) sWe[t] = We[t];
        if (threadIdx.x < D) sbe[threadIdx.x] = be[threadIdx.x];
    }
    __syncthreads();

    int cg = (threadIdx.x & 15) * 4;
    float4 vbq = *(const float4*)(bq + cg);
    float4 vbs = *(const float4*)(bs + cg);
    int h  = cg >> 3;
    int hh = (cg >> 2) & 1;

    #pragma unroll 1
    for (int it = 0; it < 4; ++it) {
        int node = blockIdx.x * 64 + it * 16 + (threadIdx.x >> 4);
        if (node >= N) return;

        float4 aq = {0,0,0,0}, as_ = {0,0,0,0};
        const float* xrow = x + (size_t)node * D;

        #pragma unroll
        for (int i = 0; i < D; i += 4) {
            float4 xv = *(const float4*)(xrow + i);
            #pragma unroll
            for (int s = 0; s < 4; ++s) {
                float xs = (&xv.x)[s];
                fma4(aq,  xs, *(const float4*)(&sW[0][(i + s) * D + cg]));
                fma4(as_, xs, *(const float4*)(&sW[1][(i + s) * D + cg]));
            }
        }
        aq.x = (aq.x + vbq.x) * QK_SCALE;
        aq.y = (aq.y + vbq.y) * QK_SCALE;
        aq.z = (aq.z + vbq.z) * QK_SCALE;
        aq.w = (aq.w + vbq.w) * QK_SCALE;
        as_.x += vbs.x; as_.y += vbs.y; as_.z += vbs.z; as_.w += vbs.w;

        uint4 pqx;
        pqx.x = f2bf(aq.x) | (f2bf(as_.x) << 16);
        pqx.y = f2bf(aq.y) | (f2bf(as_.y) << 16);
        pqx.z = f2bf(aq.z) | (f2bf(as_.z) << 16);
        pqx.w = f2bf(aq.w) | (f2bf(as_.w) << 16);
        *(uint4*)(qxr + (size_t)node * D + cg) = pqx;

        // --- A projection: A[h,i] = sum_dh q[8h+dh]*We[i,8h+dh] ---
        float part[ED];
        #pragma unroll
        for (int i = 0; i < ED; ++i) {
            float4 we4 = *(const float4*)(&sWe[i * D + cg]);
            part[i] = aq.x * we4.x + aq.y * we4.y + aq.z * we4.z + aq.w * we4.w;
        }
        float4 be4 = *(const float4*)(&sbe[cg]);
        float qb = aq.x * be4.x + aq.y * be4.y + aq.z * be4.z + aq.w * be4.w;
        #pragma unroll
        for (int i = 0; i < ED; ++i) part[i] += __shfl_xor(part[i], 1);
        qb += __shfl_xor(qb, 1);

        uint4 apk;
        apk.x = f2bf(part[hh * 8 + 0]) | (f2bf(part[hh * 8 + 1]) << 16);
        apk.y = f2bf(part[hh * 8 + 2]) | (f2bf(part[hh * 8 + 3]) << 16);
        apk.z = f2bf(part[hh * 8 + 4]) | (f2bf(part[hh * 8 + 5]) << 16);
        apk.w = f2bf(part[hh * 8 + 6]) | (f2bf(part[hh * 8 + 7]) << 16);
        *(uint4*)(Ap + (size_t)node * 64 + h * 8 + hh * 4) = apk;
        if (hh == 0) qbe[(size_t)node * 8 + h] = qb;
    }
}

// ---------------------------------------------------------------------------
// K2 fused: [proj_kv MFMA blocks | scan_a blocks]
// ---------------------------------------------------------------------------
__global__ __launch_bounds__(256) void proj_kv_scana(
    const float* __restrict__ x,
    const float* __restrict__ Wk, const float* __restrict__ bk,
    const float* __restrict__ Wv, const float* __restrict__ bv,
    uint_t* __restrict__ kvp, int N, int kvBlocks,
    const int* __restrict__ cnt, int* __restrict__ bsum)
{
    __shared__ int red[256];
    if (blockIdx.x >= kvBlocks) {
        int t = threadIdx.x;
        int i = (blockIdx.x - kvBlocks) * 256 + t;
        red[t] = (i < N) ? cnt[i] : 0;
        __syncthreads();
        for (int s = 128; s > 0; s >>= 1) {
            if (t < s) red[t] += red[t + s];
            __syncthreads();
        }
        if (t == 0) bsum[blockIdx.x - kvBlocks] = red[0];
        return;
    }

    int lane = threadIdx.x & 63;
    int wv   = threadIdx.x >> 6;
    int l = lane & 15, g = lane >> 4;

    bf16x8 Bf[2][4][2];
    #pragma unroll
    for (int ct = 0; ct < 4; ++ct)
        #pragma unroll
        for (int kh = 0; kh < 2; ++kh)
            #pragma unroll
            for (int j = 0; j < 8; ++j) {
                int k = kh * 32 + g * 8 + j;
                int c = ct * 16 + l;
                Bf[0][ct][kh][j] = (short)f2bf(Wk[k * 64 + c]);
                Bf[1][ct][kh][j] = (short)f2bf(Wv[k * 64 + c]);
            }
    float bkc[4], bvc[4];
    #pragma unroll
    for (int ct = 0; ct < 4; ++ct) {
        bkc[ct] = bk[ct * 16 + l];
        bvc[ct] = bv[ct * 16 + l];
    }

    int nt   = (N + 15) >> 4;
    int wtot = kvBlocks * 4;
    for (int t = blockIdx.x * 4 + wv; t < nt; t += wtot) {
        int n0 = t * 16;
        bf16x8 Af[2];
        const float* xr = x + (size_t)(n0 + l) * 64 + g * 8;
        #pragma unroll
        for (int kh = 0; kh < 2; ++kh) {
            float4 p0 = *(const float4*)(xr + kh * 32);
            float4 p1 = *(const float4*)(xr + kh * 32 + 4);
            Af[kh][0] = (short)f2bf(p0.x); Af[kh][1] = (short)f2bf(p0.y);
            Af[kh][2] = (short)f2bf(p0.z); Af[kh][3] = (short)f2bf(p0.w);
            Af[kh][4] = (short)f2bf(p1.x); Af[kh][5] = (short)f2bf(p1.y);
            Af[kh][6] = (short)f2bf(p1.z); Af[kh][7] = (short)f2bf(p1.w);
        }
        #pragma unroll
        for (int ct = 0; ct < 4; ++ct) {
            f32x4 ck = {0.f, 0.f, 0.f, 0.f};
            f32x4 cv = {0.f, 0.f, 0.f, 0.f};
            ck = __builtin_amdgcn_mfma_f32_16x16x32_bf16(Af[0], Bf[0][ct][0], ck, 0, 0, 0);
            ck = __builtin_amdgcn_mfma_f32_16x16x32_bf16(Af[1], Bf[0][ct][1], ck, 0, 0, 0);
            cv = __builtin_amdgcn_mfma_f32_16x16x32_bf16(Af[0], Bf[1][ct][0], cv, 0, 0, 0);
            cv = __builtin_amdgcn_mfma_f32_16x16x32_bf16(Af[1], Bf[1][ct][1], cv, 0, 0, 0);
            #pragma unroll
            for (int r = 0; r < 4; ++r) {
                int node = n0 + g * 4 + r;
                uint_t pk = f2bf(ck[r] + bkc[ct]) | (f2bf(cv[r] + bvc[ct]) << 16);
                kvp[(size_t)node * 64 + ct * 16 + l] = pk;
            }
        }
    }
}

// ---------------------------------------------------------------------------
// scan_c (merged with scan_b): every block redundantly scans the block sums.
// ---------------------------------------------------------------------------
__global__ __launch_bounds__(256) void scan_c(
    const int* __restrict__ cnt, const int* __restrict__ bsum,
    int* __restrict__ row_start, int* __restrict__ cursor, int N, int E, int nb)
{
    __shared__ int sb[256];
    __shared__ int sh[256];
    int t = threadIdx.x;
    int bv = (t < nb) ? bsum[t] : 0;
    sb[t] = bv;
    __syncthreads();
    for (int s = 1; s < 256; s <<= 1) {
        int a = (t >= s) ? sb[t - s] : 0;
        __syncthreads();
        sb[t] += a;
        __syncthreads();
    }
    int boff = sb[blockIdx.x] - bsum[blockIdx.x];   // exclusive block offset

    int i = blockIdx.x * 256 + t;
    int v = (i < N) ? cnt[i] : 0;
    sh[t] = v;
    __syncthreads();
    for (int s = 1; s < 256; s <<= 1) {
        int a = (t >= s) ? sh[t - s] : 0;
        __syncthreads();
        sh[t] += a;
        __syncthreads();
    }
    int excl = sh[t] - v + boff;
    if (i < N) { row_start[i] = excl; cursor[i] = excl; }
    if (i == N - 1) row_start[N] = E;
}

// ---------------------------------------------------------------------------
// K5: payload scatter. srcs_s[pos] + ea_s[pos] (bf16 row) in CSR order.
// ---------------------------------------------------------------------------
__global__ __launch_bounds__(256) void csr_scatter(
    const int* __restrict__ ei, const float4* __restrict__ ea4,
    int* __restrict__ cursor, int* __restrict__ srcs_s,
    uint_t* __restrict__ ea_s, int E)
{
    int gid = blockIdx.x * 256 + threadIdx.x;
    if (gid >= E) return;
    int src = ei[gid];
    int dst = ei[E + gid];
    float4 r0 = ea4[(size_t)gid * 4 + 0];
    float4 r1 = ea4[(size_t)gid * 4 + 1];
    float4 r2 = ea4[(size_t)gid * 4 + 2];
    float4 r3 = ea4[(size_t)gid * 4 + 3];
    int pos = atomicAdd(&cursor[dst], 1);
    srcs_s[pos] = src;
    uint4 p0, p1;
    p0.x = f2bf(r0.x) | (f2bf(r0.y) << 16);
    p0.y = f2bf(r0.z) | (f2bf(r0.w) << 16);
    p0.z = f2bf(r1.x) | (f2bf(r1.y) << 16);
    p0.w = f2bf(r1.z) | (f2bf(r1.w) << 16);
    p1.x = f2bf(r2.x) | (f2bf(r2.y) << 16);
    p1.y = f2bf(r2.z) | (f2bf(r2.w) << 16);
    p1.z = f2bf(r3.x) | (f2bf(r3.y) << 16);
    p1.w = f2bf(r3.z) | (f2bf(r3.w) << 16);
    *(uint4*)(ea_s + (size_t)pos * 8)     = p0;
    *(uint4*)(ea_s + (size_t)pos * 8 + 4) = p1;
}

// ---------------------------------------------------------------------------
// K6: pull gather (R18/R20 best config).
// ---------------------------------------------------------------------------
__global__ __launch_bounds__(256, 4) void node_gather(
    const int*   __restrict__ row_start, // [N+1]
    const int*   __restrict__ srcs_s,    // [E] CSR-ordered src
    const uint_t* __restrict__ ea_s,     // [E*8] CSR-ordered bf16x2
    const float* __restrict__ We, const float* __restrict__ be,
    const uint_t* __restrict__ qxr, const uint_t* __restrict__ kvp,
    const uint_t* __restrict__ Ap, const float* __restrict__ qbe,
    const float* __restrict__ Wbeta,
    float* __restrict__ out, float* __restrict__ S1p, float* __restrict__ S2p,
    int N)
{
    __shared__ float l1[4][D];
    __shared__ float l2[4][D];
    int lane = threadIdx.x & 63;
    int w    = threadIdx.x >> 6;
    int h    = lane & 7;
    int e    = lane >> 3;
    int cmix = h * 8 + e;

    float w0[8], w1[8];
    #pragma unroll
    for (int j = 0; j < 8; ++j) {
        w0[j] = We[(2 * e)     * D + h * 8 + j];
        w1[j] = We[(2 * e + 1) * D + h * 8 + j];
    }
    float bev = be[cmix];
    float wb0 = Wbeta[cmix], wb1 = Wbeta[D + cmix], wb2 = Wbeta[2 * D + cmix];

    float s1bn = 0.f, s2bn = 0.f;
    int stride = gridDim.x * 4;

    for (int nid = blockIdx.x * 4 + w; nid < N; nid += stride) {
        int rs  = row_start[nid];
        int deg = row_start[nid + 1] - rs;

        const uint4* qxp = (const uint4*)(qxr + (size_t)nid * D + h * 8);
        uint4 qx0 = qxp[0], qx1 = qxp[1];
        float q8[8];
        q8[0] = bf_lo(qx0.x); q8[1] = bf_lo(qx0.y);
        q8[2] = bf_lo(qx0.z); q8[3] = bf_lo(qx0.w);
        q8[4] = bf_lo(qx1.x); q8[5] = bf_lo(qx1.y);
        q8[6] = bf_lo(qx1.z); q8[7] = bf_lo(qx1.w);
        uint_t xru0 = (e & 2) ? ((e & 1) ? qx0.w : qx0.z)
                              : ((e & 1) ? qx0.y : qx0.x);
        uint_t xru1 = (e & 2) ? ((e & 1) ? qx1.w : qx1.z)
                              : ((e & 1) ? qx1.y : qx1.x);
        float xrv = bf_hi((e & 4) ? xru1 : xru0);

        const uint4* app = (const uint4*)(Ap + (size_t)nid * 64 + h * 8);
        uint4 au0 = app[0], au1 = app[1];
        float a16[ED];
        #pragma unroll
        for (int j = 0; j < 4; ++j) {
            a16[j * 2]         = bf_lo((&au0.x)[j]);
            a16[j * 2 + 1]     = bf_hi((&au0.x)[j]);
            a16[8 + j * 2]     = bf_lo((&au1.x)[j]);
            a16[8 + j * 2 + 1] = bf_hi((&au1.x)[j]);
        }
        float qbeh = qbe[(size_t)nid * 8 + h];

        float acc[8] = {0,0,0,0,0,0,0,0};
        float sv[ED] = {0,0,0,0,0,0,0,0,0,0,0,0,0,0,0,0};
        float den = 0.f;

        int src_next = (e < deg) ? srcs_s[rs + e] : 0;

        for (int j0 = 0; j0 < deg; j0 += 8) {
            int src = src_next;
            {
                int enx = j0 + 8 + e;
                src_next = (enx < deg) ? srcs_s[rs + enx] : 0;
            }
            int eidx = j0 + e;
            bool valid = eidx < deg;
            int ce = valid ? eidx : 0;

            const uint4* kp = (const uint4*)(kvp + (size_t)src * 64 + h * 8);
            uint4 k0 = kp[0], k1 = kp[1];
            const uint4* ep = (const uint4*)(ea_s + (size_t)(rs + ce) * 8);
            uint4 u0 = ep[0], u1 = ep[1];

            float ex[ED];
            #pragma unroll
            for (int j = 0; j < 4; ++j) {
                ex[j * 2]         = bf_lo((&u0.x)[j]);
                ex[j * 2 + 1]     = bf_hi((&u0.x)[j]);
                ex[8 + j * 2]     = bf_lo((&u1.x)[j]);
                ex[8 + j * 2 + 1] = bf_hi((&u1.x)[j]);
            }
            float c = qbeh;
            c += q8[0] * bf_lo(k0.x); c += q8[1] * bf_lo(k0.y);
            c += q8[2] * bf_lo(k0.z); c += q8[3] * bf_lo(k0.w);
            c += q8[4] * bf_lo(k1.x); c += q8[5] * bf_lo(k1.y);
            c += q8[6] * bf_lo(k1.z); c += q8[7] * bf_lo(k1.w);
            #pragma unroll
            for (int i = 0; i < ED; ++i) c += ex[i] * a16[i];

            float p = valid ? __expf(c) : 0.f;
            den += p;
            acc[0] += p * bf_hi(k0.x); acc[1] += p * bf_hi(k0.y);
            acc[2] += p * bf_hi(k0.z); acc[3] += p * bf_hi(k0.w);
            acc[4] += p * bf_hi(k1.x); acc[5] += p * bf_hi(k1.y);
            acc[6] += p * bf_hi(k1.z); acc[7] += p * bf_hi(k1.w);
            #pragma unroll
            for (int i = 0; i < ED; ++i) sv[i] += p * ex[i];
        }

        den += __shfl_xor(den, 8);
        den += __shfl_xor(den, 16);
        den += __shfl_xor(den, 32);

        float u[8];
        #pragma unroll
        for (int j = 0; j < 8; ++j) {
            int i0 = ((j & 6) << 1) | (j & 1);
            float k = (e & 1) ? sv[i0 | 2] : sv[i0];
            float s = (e & 1) ? sv[i0] : sv[i0 | 2];
            u[j] = k + __shfl_xor(s, 8);
        }
        float v2[4];
        #pragma unroll
        for (int j = 0; j < 4; ++j) {
            int j0 = ((j & 2) << 1) | (j & 1);
            float k = (e & 2) ? u[j0 | 2] : u[j0];
            float s = (e & 2) ? u[j0] : u[j0 | 2];
            v2[j] = k + __shfl_xor(s, 16);
        }
        float S0, S1;
        {
            float k0 = (e & 4) ? v2[2] : v2[0];
            float s0 = (e & 4) ? v2[0] : v2[2];
            S0 = k0 + __shfl_xor(s0, 32);
            float k1 = (e & 4) ? v2[3] : v2[1];
            float s1 = (e & 4) ? v2[1] : v2[3];
            S1 = k1 + __shfl_xor(s1, 32);
        }

        float cj[8];
        #pragma unroll
        for (int j = 0; j < 8; ++j) cj[j] = S0 * w0[j] + S1 * w1[j];
        float esum = khreduce8(cj, e);
        float vsum = khreduce8(acc, e);

        float o = (vsum + esum + bev * den) / (den + 1e-16f);

        float tb  = o * wb0 + xrv * wb1 + (o - xrv) * wb2;
        #pragma unroll
        for (int s = 1; s < 64; s <<= 1) tb += __shfl_xor(tb, s);
        float g  = 1.f / (1.f + __expf(-tb));
        float o2 = g * xrv + (1.f - g) * o;
        out[(size_t)nid * D + cmix] = o2;
        s1bn += o2; s2bn += o2 * o2;
    }

    l1[w][cmix] = s1bn; l2[w][cmix] = s2bn;
    __syncthreads();
    if (threadIdx.x < D) {
        float a = l1[0][threadIdx.x] + l1[1][threadIdx.x]
                + l1[2][threadIdx.x] + l1[3][threadIdx.x];
        float b = l2[0][threadIdx.x] + l2[1][threadIdx.x]
                + l2[2][threadIdx.x] + l2[3][threadIdx.x];
        unsafeAtomicAdd(&S1p[threadIdx.x * 64], a);
        unsafeAtomicAdd(&S2p[threadIdx.x * 64], b);
    }
}

// ---------------------------------------------------------------------------
// K7: batchnorm finalize + apply + LeakyReLU, float4 in place on d_out.
// ---------------------------------------------------------------------------
__global__ __launch_bounds__(256) void bn_apply(
    float4* __restrict__ out, const float* __restrict__ S1p,
    const float* __restrict__ S2p, const float* __restrict__ gamma,
    const float* __restrict__ beta, int total4, float invN)
{
    int gid = blockIdx.x * 256 + threadIdx.x;
    if (gid >= total4) return;
    int col = (gid & 15) * 4;
    float4 g4 = *(const float4*)(gamma + col);
    float4 b4 = *(const float4*)(beta + col);
    float4 y  = out[gid];
    #pragma unroll
    for (int j = 0; j < 4; ++j) {
        float mean = S1p[(col + j) * 64] * invN;
        float var  = S2p[(col + j) * 64] * invN - mean * mean;
        float sc   = (&g4.x)[j] * rsqrtf(var + 1e-5f);
        float sh   = (&b4.x)[j] - mean * sc;
        float tv   = (&y.x)[j] * sc + sh;
        (&y.x)[j]  = (tv >= 0.f) ? tv : 0.01f * tv;
    }
    out[gid] = y;
}

// ---------------------------------------------------------------------------
extern "C" void kernel_launch(void* const* d_in, const int* in_sizes, int n_in,
                              void* d_out, int out_size, void* d_ws, size_t ws_size,
                              hipStream_t stream)
{
    const float* x     = (const float*)d_in[0];
    const int*   ei    = (const int*)  d_in[1];
    const float* ea    = (const float*)d_in[2];
    const float* Wq    = (const float*)d_in[3];
    const float* bq    = (const float*)d_in[4];
    const float* Wk    = (const float*)d_in[5];
    const float* bk    = (const float*)d_in[6];
    const float* Wv    = (const float*)d_in[7];
    const float* bv    = (const float*)d_in[8];
    const float* We    = (const float*)d_in[9];
    const float* be    = (const float*)d_in[10];
    const float* Wskip = (const float*)d_in[11];
    const float* bskip = (const float*)d_in[12];
    const float* Wbeta = (const float*)d_in[13];
    const float* gamma = (const float*)d_in[14];
    const float* betab = (const float*)d_in[15];

    int N = in_sizes[0] / D;   // 50000
    int E = in_sizes[1] / 2;   // 800000

    // ws layout (uint units)
    int*    ws        = (int*)d_ws;
    int*    cnt       = ws;                         // 50000 (also scatter cursor)
    float*  S1p       = (float*)(ws + 50000);       // 4096 padded col sums
    float*  S2p       = (float*)(ws + 54096);       // 4096
    int*    row_start = ws + 58192;                 // 50004
    int*    bsum      = ws + 108240;                // 256 (16B aligned)
    int*    srcs_s    = ws + 108544;                // 800000
    uint_t* ea_s      = (uint_t*)(ws + 908544);     // 6400000
    uint_t* kvp       = (uint_t*)(ws + 7308544);    // 3200000
    uint_t* qxr       = (uint_t*)(ws + 10508544);   // 3200000 (packed q|xr)
    uint_t* Ap        = (uint_t*)(ws + 13708544);   // 3200000
    float*  qbe       = (float*)(ws + 16908544);    // 400000

    // zero cnt + S1p + S2p (contiguous)
    hipMemsetAsync(d_ws, 0, (size_t)58192 * sizeof(int), stream);

    int projB = (N + 63) / 64;      // 782
    int histB = (E + 255) / 256;    // 3125
    proj_qs_hist<<<projB + histB, 256, 0, stream>>>(
        x, Wq, bq, Wskip, bskip, We, be,
        qxr, Ap, qbe, N, ei, cnt, E, projB);

    int scanB = (N + 255) / 256;    // 196
    int kvB   = 196;                // MFMA waves: 784, ~4 node-tiles each
    proj_kv_scana<<<kvB + scanB, 256, 0, stream>>>(
        x, Wk, bk, Wv, bv, kvp, N, kvB, cnt, bsum);

    scan_c<<<scanB, 256, 0, stream>>>(cnt, bsum, row_start, cnt, N, E, scanB);

    csr_scatter<<<(E + 255) / 256, 256, 0, stream>>>(
        ei, (const float4*)ea, cnt, srcs_s, ea_s, E);

    node_gather<<<1024, 256, 0, stream>>>(
        row_start, srcs_s, ea_s, We, be, qxr, kvp, Ap, qbe, Wbeta,
        (float*)d_out, S1p, S2p, N);

    bn_apply<<<(N * 16 + 255) / 256, 256, 0, stream>>>(
        (float4*)d_out, S1p, S2p, gamma, betab, N * 16, 1.0f / (float)N);
}